// Round 1
// baseline (197.470 us; speedup 1.0000x reference)
//
#include <hip/hip_runtime.h>

// out[b,o] = sum_{k<4} w[o*4+k] * x[b, o*4+k] + t[b] * tw[o]
// B=1024, NUM_OUT=8192, BF=4, NUM_IN=32768. All fp32.
// Memory-bound: 128 MiB x-read + 32 MiB out-write -> ~27 us floor at 6.3 TB/s.

constexpr int BATCH   = 1024;
constexpr int NUM_OUT = 8192;

__global__ __launch_bounds__(256) void DendriticBranchLayerSparse_62689342652745_kernel(
    const float* __restrict__ x,        // [B, 32768]
    const float* __restrict__ t,        // [B]
    const float* __restrict__ w,        // [32768]
    const float* __restrict__ tw,       // [8192] (stored as [8192,1])
    float* __restrict__ out)            // [B, 8192]
{
    const int idx = blockIdx.x * blockDim.x + threadIdx.x;  // one output element
    const int b = idx >> 13;          // idx / 8192
    const int o = idx & (NUM_OUT - 1);

    // x group for (b,o) starts at b*32768 + o*4 == idx*4 -> 16B-aligned float4
    const float4 xv = *reinterpret_cast<const float4*>(x + (size_t)idx * 4);
    const float4 wv = *reinterpret_cast<const float4*>(w + (size_t)o * 4);

    float r = xv.x * wv.x + xv.y * wv.y + xv.z * wv.z + xv.w * wv.w;
    r += t[b] * tw[o];

    out[idx] = r;
}

extern "C" void kernel_launch(void* const* d_in, const int* in_sizes, int n_in,
                              void* d_out, int out_size, void* d_ws, size_t ws_size,
                              hipStream_t stream) {
    const float* x  = (const float*)d_in[0];   // [1024, 32768]
    const float* t  = (const float*)d_in[1];   // [1024]
    const float* w  = (const float*)d_in[2];   // [32768]
    const float* tw = (const float*)d_in[3];   // [8192, 1]
    float* out = (float*)d_out;                // [1024, 8192]

    const int total = BATCH * NUM_OUT;         // 8,388,608
    const int block = 256;
    const int grid = total / block;            // 32768

    DendriticBranchLayerSparse_62689342652745_kernel<<<grid, block, 0, stream>>>(
        x, t, w, tw, out);
}